// Round 1
// baseline (217.103 us; speedup 1.0000x reference)
//
#include <hip/hip_runtime.h>
#include <math.h>

#define EPS 1e-5f

constexpr int Bc = 64, Pc = 68, Hc = 64, Wc = 64;
constexpr int NPIX  = Hc * Wc;        // 4096 pixels per tile
constexpr int NTILE = Bc * Pc;        // 4352 tiles
constexpr int BLK   = 256;            // threads per block
constexpr int PPT   = NPIX / BLK;     // 16 pixels per thread
constexpr int NSLOT = 64;             // f64 accumulator slots (avoid same-address atomic serialization)

constexpr float LOG2E = 1.44269504088896340736f;
constexpr float LN2   = 0.69314718055994530942f;

// Block-wide sum reduction (256 threads = 4 waves of 64).
__device__ __forceinline__ float block_reduce_sum(float v, float* sbuf) {
    __syncthreads();  // protect sbuf from previous use
    #pragma unroll
    for (int o = 32; o > 0; o >>= 1) v += __shfl_down(v, o, 64);
    const int lane = threadIdx.x & 63;
    const int wid  = threadIdx.x >> 6;
    if (lane == 0) sbuf[wid] = v;
    __syncthreads();
    if (threadIdx.x == 0) sbuf[4] = sbuf[0] + sbuf[1] + sbuf[2] + sbuf[3];
    __syncthreads();
    return sbuf[4];
}

// Zero the 64 f64 slots + completion counter. Runs BEFORE the main kernel
// (replaces the trailing reduce kernel; ws is re-poisoned every iteration
// so this must be inside the captured launch sequence).
__global__ __launch_bounds__(64)
void init_kernel(double* __restrict__ acc, unsigned int* __restrict__ cnt) {
    const int t = threadIdx.x;
    if (t < NSLOT) acc[t] = 0.0;
    if (t == 0)    *cnt  = 0u;
}

__global__ __launch_bounds__(BLK)
void gauss_kld_fused_kernel(const float* __restrict__ hm,
                            const float* __restrict__ means,
                            const float* __restrict__ cov,
                            double* __restrict__ acc,
                            unsigned int* __restrict__ cnt,
                            float* __restrict__ out) {
    const int tile = blockIdx.x;
    const float* __restrict__ h = hm + (size_t)tile * NPIX;

    const float mx  = means[tile * 2 + 0];
    const float my  = means[tile * 2 + 1];
    const float s00 = cov[tile * 4 + 0];
    const float s01 = cov[tile * 4 + 1];
    const float s10 = cov[tile * 4 + 2];
    const float s11 = cov[tile * 4 + 3];
    const float det = s00 * s11 - s01 * s10 + EPS;
    // Fold -0.5 * log2(e) / det into the quadratic so pass 1 is
    // 2 FMA + 1 v_exp_f32 per pixel (exp2 is the raw HW op).
    const float kf  = -0.5f * LOG2E / det;
    const float axx =  kf * s11;
    const float axy = -kf * (s01 + s10);
    const float ayy =  kf * s00;

    const int t = threadIdx.x;

    float ev[PPT];   // e = 2^l2 = exp(log-prob), unnormalized
    float hv[PPT];
    float esum = 0.0f, hlog = 0.0f, hsum = 0.0f;

    // Coalesced float4 loads: float4 index v = kk*256 + t, pixels [4v, 4v+4)
    #pragma unroll
    for (int kk = 0; kk < PPT / 4; kk++) {
        const int v = kk * BLK + t;
        const float4 h4 = reinterpret_cast<const float4*>(h)[v];
        const float dy  = (float)(v >> 4) - my;          // row
        const float dx0 = (float)((v & 15) << 2) - mx;   // first col of the float4
        const float txy = axy * dy;
        const float tyy = ayy * dy * dy;
        #pragma unroll
        for (int c = 0; c < 4; c++) {
            const float dx = dx0 + (float)c;
            const float l2 = fmaf(fmaf(axx, dx, txy), dx, tyy); // log2-domain log-prob
            const float e  = __builtin_amdgcn_exp2f(l2);
            ev[kk * 4 + c] = e;
            esum += e;
        }
        hv[kk * 4 + 0] = h4.x; hv[kk * 4 + 1] = h4.y;
        hv[kk * 4 + 2] = h4.z; hv[kk * 4 + 3] = h4.w;
        // h*log2(h) done here: hidden under global-load latency
        #pragma unroll
        for (int c = 0; c < 4; c++) {
            const float hh = hv[kk * 4 + c];
            hsum += hh;
            hlog = fmaf(hh, __builtin_amdgcn_logf(fmaxf(hh, 1e-38f)), hlog);
        }
    }

    __shared__ float sbuf[8];
    const float S    = block_reduce_sum(esum, sbuf);
    const float cadd = EPS * S;                         // log(e/S+EPS) = log((e+EPS*S)/S)
    const float lnS  = __builtin_amdgcn_logf(S) * LN2;  // natural log of S

    // Pass 2: 1 add + 1 v_log_f32 + 1 FMA per pixel (was exp+mul+add+2log+sub)
    float kb = 0.0f;
    #pragma unroll
    for (int i = 0; i < PPT; i++) {
        kb = fmaf(hv[i], __builtin_amdgcn_logf(ev[i] + cadd), kb);
    }
    // sum_i h*ln(h) - h*ln(pr+EPS) = LN2*(hlog - kb) + lnS*hsum
    const float contrib   = fmaf(lnS, hsum, LN2 * (hlog - kb));
    const float tile_sum  = block_reduce_sum(contrib, sbuf);

    // Cross-tile reduction fused in: 64-slot f64 atomics + last-block finalize.
    __shared__ int is_last;
    if (threadIdx.x == 0) {
        atomicAdd(&acc[tile & (NSLOT - 1)], (double)tile_sum);
        __threadfence();  // release: slot add visible before counter bump
        is_last = (atomicAdd(cnt, 1u) == (unsigned)(gridDim.x - 1)) ? 1 : 0;
    }
    __syncthreads();
    if (is_last && threadIdx.x < 64) {
        // Read slots through the atomic path: per-XCD L2s are not coherent,
        // plain loads could see stale (poisoned) lines.
        double v = atomicAdd(&acc[threadIdx.x], 0.0);
        #pragma unroll
        for (int o = 32; o > 0; o >>= 1) v += __shfl_down(v, o, 64);
        if (threadIdx.x == 0) out[0] = (float)(v / (double)NTILE);
    }
}

extern "C" void kernel_launch(void* const* d_in, const int* in_sizes, int n_in,
                              void* d_out, int out_size, void* d_ws, size_t ws_size,
                              hipStream_t stream) {
    const float* hm    = (const float*)d_in[0];
    const float* means = (const float*)d_in[1];
    const float* cov   = (const float*)d_in[2];
    float* out = (float*)d_out;

    double*       acc = (double*)d_ws;                     // 64 * 8 B
    unsigned int* cnt = (unsigned int*)((char*)d_ws + NSLOT * sizeof(double));

    init_kernel<<<1, 64, 0, stream>>>(acc, cnt);
    gauss_kld_fused_kernel<<<NTILE, BLK, 0, stream>>>(hm, means, cov, acc, cnt, out);
}

// Round 2
// 209.677 us; speedup vs baseline: 1.0354x; 1.0354x over previous
//
#include <hip/hip_runtime.h>
#include <math.h>

#define EPS 1e-5f

constexpr int Bc = 64, Pc = 68, Hc = 64, Wc = 64;
constexpr int NPIX  = Hc * Wc;        // 4096 pixels per tile
constexpr int NTILE = Bc * Pc;        // 4352 tiles
constexpr int BLK   = 256;            // threads per block
constexpr int NSLOT = 64;             // f64 accumulator slots

constexpr float LN2 = 0.69314718055994530942f;
constexpr float LOG2E = 1.44269504088896340736f;

__device__ __forceinline__ float block_reduce_sum(float v, float* sbuf) {
    __syncthreads();
    #pragma unroll
    for (int o = 32; o > 0; o >>= 1) v += __shfl_down(v, o, 64);
    const int lane = threadIdx.x & 63;
    const int wid  = threadIdx.x >> 6;
    if (lane == 0) sbuf[wid] = v;
    __syncthreads();
    if (threadIdx.x == 0) sbuf[4] = sbuf[0] + sbuf[1] + sbuf[2] + sbuf[3];
    __syncthreads();
    return sbuf[4];
}

__global__ __launch_bounds__(64)
void init_kernel(double* __restrict__ acc, unsigned int* __restrict__ cnt) {
    const int t = threadIdx.x;
    if (t < NSLOT) acc[t] = 0.0;
    if (t == 0)    *cnt  = 0u;
}

__global__ __launch_bounds__(BLK)
void gauss_kld_fused_kernel(const float* __restrict__ hm,
                            const float* __restrict__ means,
                            const float* __restrict__ cov,
                            double* __restrict__ acc,
                            unsigned int* __restrict__ cnt,
                            float* __restrict__ out) {
    const int tile = blockIdx.x;
    const float4* __restrict__ hp4 =
        reinterpret_cast<const float4*>(hm + (size_t)tile * NPIX);

    const float mx  = means[tile * 2 + 0];
    const float my  = means[tile * 2 + 1];
    const float s00 = cov[tile * 4 + 0];
    const float s01 = cov[tile * 4 + 1];
    const float s10 = cov[tile * 4 + 2];
    const float s11 = cov[tile * 4 + 3];
    const float det = s00 * s11 - s01 * s10 + EPS;
    // Fold -0.5*log2(e)/det into the quadratic: pass 1 = 2 FMA + 1 v_exp per px.
    const float kf  = -0.5f * LOG2E / det;
    const float axx =  kf * s11;
    const float axy = -kf * (s01 + s10);
    const float ayy =  kf * s00;

    const int t = threadIdx.x;

    // 8 NAMED float4s — no indexable array anywhere, cannot be demoted to
    // scratch (round-1 lesson: indexed arrays + failed unroll -> VGPR=24,
    // scratch-latency-bound at 6% VALUBusy).
    float4 hv0, hv1, hv2, hv3;
    float4 ev0, ev1, ev2, ev3;
    float esum = 0.0f, hlog = 0.0f, hsum = 0.0f;

// pixel float4 index v = KK*256+t; pixels [4v,4v+4); row=v>>4, col0=(v&15)*4.
// All logs here are log2 (v_log_f32); scaled by LN2 at the end.
#define P1(KK, HV, EV) do {                                                    \
    const int v = (KK) * BLK + t;                                              \
    HV = hp4[v];                                                               \
    const float dy  = (float)(v >> 4) - my;                                    \
    const float dxa = (float)((v & 15) << 2) - mx;                             \
    const float txy = axy * dy;                                                \
    const float tyy = ayy * dy * dy;                                           \
    const float dxb = dxa + 1.0f, dxc = dxa + 2.0f, dxd = dxa + 3.0f;          \
    EV.x = __builtin_amdgcn_exp2f(fmaf(fmaf(axx, dxa, txy), dxa, tyy));        \
    EV.y = __builtin_amdgcn_exp2f(fmaf(fmaf(axx, dxb, txy), dxb, tyy));        \
    EV.z = __builtin_amdgcn_exp2f(fmaf(fmaf(axx, dxc, txy), dxc, tyy));        \
    EV.w = __builtin_amdgcn_exp2f(fmaf(fmaf(axx, dxd, txy), dxd, tyy));        \
    esum += (EV.x + EV.y) + (EV.z + EV.w);                                     \
    hsum += (HV.x + HV.y) + (HV.z + HV.w);                                     \
    hlog = fmaf(HV.x, __builtin_amdgcn_logf(fmaxf(HV.x, 1e-38f)), hlog);       \
    hlog = fmaf(HV.y, __builtin_amdgcn_logf(fmaxf(HV.y, 1e-38f)), hlog);       \
    hlog = fmaf(HV.z, __builtin_amdgcn_logf(fmaxf(HV.z, 1e-38f)), hlog);       \
    hlog = fmaf(HV.w, __builtin_amdgcn_logf(fmaxf(HV.w, 1e-38f)), hlog);       \
} while (0)

    P1(0, hv0, ev0);
    P1(1, hv1, ev1);
    P1(2, hv2, ev2);
    P1(3, hv3, ev3);
#undef P1

    __shared__ float sbuf[8];
    const float S    = block_reduce_sum(esum, sbuf);
    const float cadd = EPS * S;                            // log(e/S+EPS) = log2(e+EPS*S) - log2(S)
    const float l2S  = __builtin_amdgcn_logf(S);           // log2(S)

    float kb = 0.0f;
#define P2(HV, EV) do {                                                        \
    kb = fmaf(HV.x, __builtin_amdgcn_logf(EV.x + cadd), kb);                   \
    kb = fmaf(HV.y, __builtin_amdgcn_logf(EV.y + cadd), kb);                   \
    kb = fmaf(HV.z, __builtin_amdgcn_logf(EV.z + cadd), kb);                   \
    kb = fmaf(HV.w, __builtin_amdgcn_logf(EV.w + cadd), kb);                   \
} while (0)

    P2(hv0, ev0);
    P2(hv1, ev1);
    P2(hv2, ev2);
    P2(hv3, ev3);
#undef P2

    // sum h*ln(h) - h*ln(pr+EPS) = LN2 * (hlog - kb + log2(S)*hsum)
    const float contrib  = LN2 * (fmaf(l2S, hsum, hlog - kb));
    const float tile_sum = block_reduce_sum(contrib, sbuf);

    // Fused cross-tile reduction: 64-slot f64 atomics + last-block finalize.
    __shared__ int is_last;
    if (threadIdx.x == 0) {
        atomicAdd(&acc[tile & (NSLOT - 1)], (double)tile_sum);
        __threadfence();  // release: slot add visible before counter bump
        is_last = (atomicAdd(cnt, 1u) == (unsigned)(gridDim.x - 1)) ? 1 : 0;
    }
    __syncthreads();
    if (is_last && threadIdx.x < 64) {
        // Atomic-path read: per-XCD L2s are not cross-coherent.
        double v = atomicAdd(&acc[threadIdx.x], 0.0);
        #pragma unroll
        for (int o = 32; o > 0; o >>= 1) v += __shfl_down(v, o, 64);
        if (threadIdx.x == 0) out[0] = (float)(v / (double)NTILE);
    }
}

extern "C" void kernel_launch(void* const* d_in, const int* in_sizes, int n_in,
                              void* d_out, int out_size, void* d_ws, size_t ws_size,
                              hipStream_t stream) {
    const float* hm    = (const float*)d_in[0];
    const float* means = (const float*)d_in[1];
    const float* cov   = (const float*)d_in[2];
    float* out = (float*)d_out;

    double*       acc = (double*)d_ws;                     // 64 * 8 B
    unsigned int* cnt = (unsigned int*)((char*)d_ws + NSLOT * sizeof(double));

    init_kernel<<<1, 64, 0, stream>>>(acc, cnt);
    gauss_kld_fused_kernel<<<NTILE, BLK, 0, stream>>>(hm, means, cov, acc, cnt, out);
}

// Round 3
// 106.713 us; speedup vs baseline: 2.0345x; 1.9649x over previous
//
#include <hip/hip_runtime.h>
#include <math.h>

#define EPS 1e-5f

constexpr int Bc = 64, Pc = 68, Hc = 64, Wc = 64;
constexpr int NPIX  = Hc * Wc;   // 4096 pixels per tile
constexpr int NTILE = Bc * Pc;   // 4352 tiles
constexpr int BLK   = 256;       // threads per block
constexpr int PPT   = NPIX / BLK; // 16 pixels per thread

constexpr float LOG2E = 1.44269504088896340736f;

// Block-wide sum reduction (256 threads = 4 waves of 64).
__device__ __forceinline__ float block_reduce_sum(float v, float* sbuf) {
    __syncthreads();  // protect sbuf from previous use
    #pragma unroll
    for (int o = 32; o > 0; o >>= 1) v += __shfl_down(v, o, 64);
    const int lane = threadIdx.x & 63;
    const int wid  = threadIdx.x >> 6;
    if (lane == 0) sbuf[wid] = v;
    __syncthreads();
    if (threadIdx.x == 0) {
        float s = sbuf[0] + sbuf[1] + sbuf[2] + sbuf[3];
        sbuf[4] = s;
    }
    __syncthreads();
    return sbuf[4];
}

__global__ __launch_bounds__(BLK)
void gauss_kld_tile_kernel(const float* __restrict__ hm,
                           const float* __restrict__ means,
                           const float* __restrict__ cov,
                           float* __restrict__ partial) {
    const int tile = blockIdx.x;
    const float* __restrict__ h = hm + (size_t)tile * NPIX;

    const float mx  = means[tile * 2 + 0];
    const float my  = means[tile * 2 + 1];
    const float s00 = cov[tile * 4 + 0];
    const float s01 = cov[tile * 4 + 1];
    const float s10 = cov[tile * 4 + 2];
    const float s11 = cov[tile * 4 + 3];
    const float det = s00 * s11 - s01 * s10 + EPS;
    // Fold -0.5 * log2(e) / det into the coefficients: per-pixel work in
    // pass 1 is then 2 FMA + 1 raw v_exp_f32 (exp2), no scale mul.
    const float kf  = -0.5f * LOG2E / det;
    const float c_xx =  kf * s11;
    const float c_xy = -kf * (s01 + s10);
    const float c_yy =  kf * s00;

    const int t = threadIdx.x;

    float ev[PPT];   // exp(log-prob), unnormalized — stored so pass 2 needs no exp
    float hv[PPT];
    float esum = 0.0f;

    // Coalesced float4 loads: float4 index v = k*256 + t, pixels [4v, 4v+4)
    #pragma unroll
    for (int k = 0; k < PPT / 4; k++) {
        const int v = k * BLK + t;
        const float4 h4 = reinterpret_cast<const float4*>(h)[v];
        hv[k * 4 + 0] = h4.x;
        hv[k * 4 + 1] = h4.y;
        hv[k * 4 + 2] = h4.z;
        hv[k * 4 + 3] = h4.w;
        const int base = v * 4;
        #pragma unroll
        for (int c = 0; c < 4; c++) {
            const int idx = base + c;
            const float dy = (float)(idx >> 6) - my;   // row = y
            const float dx = (float)(idx & 63) - mx;   // col = x
            // log2-domain log-prob: quad already scaled by -0.5*log2(e)
            const float l2 = fmaf(fmaf(c_xx, dx, c_xy * dy), dx, c_yy * dy * dy);
            const float e  = __builtin_amdgcn_exp2f(l2);
            ev[k * 4 + c] = e;
            esum += e;
        }
    }

    __shared__ float sbuf[8];
    const float S = block_reduce_sum(esum, sbuf);
    const float invS = 1.0f / S;

    float kl = 0.0f;
    #pragma unroll
    for (int i = 0; i < PPT; i++) {
        const float pr = ev[i] * invS;   // no re-exp: ev stored from pass 1
        const float hvi = hv[i];
        // xlogy(hm,hm) - hm*log(pr+EPS); hm>0 in this problem, guard anyway
        if (hvi > 0.0f) {
            kl += hvi * (__logf(hvi) - __logf(pr + EPS));
        } else {
            kl += -hvi * __logf(pr + EPS);
        }
    }

    const float tile_sum = block_reduce_sum(kl, sbuf);
    if (threadIdx.x == 0) partial[tile] = tile_sum;
}

__global__ __launch_bounds__(BLK)
void gauss_kld_reduce_kernel(const float* __restrict__ partial,
                             float* __restrict__ out) {
    float s = 0.0f;
    for (int i = threadIdx.x; i < NTILE; i += BLK) s += partial[i];
    __shared__ float sbuf[8];
    const float tot = block_reduce_sum(s, sbuf);
    if (threadIdx.x == 0) out[0] = tot / (float)NTILE;
}

extern "C" void kernel_launch(void* const* d_in, const int* in_sizes, int n_in,
                              void* d_out, int out_size, void* d_ws, size_t ws_size,
                              hipStream_t stream) {
    const float* hm    = (const float*)d_in[0];
    const float* means = (const float*)d_in[1];
    const float* cov   = (const float*)d_in[2];
    float* out = (float*)d_out;
    float* partial = (float*)d_ws;  // NTILE floats

    gauss_kld_tile_kernel<<<NTILE, BLK, 0, stream>>>(hm, means, cov, partial);
    gauss_kld_reduce_kernel<<<1, BLK, 0, stream>>>(partial, out);
}

// Round 5
// 100.599 us; speedup vs baseline: 2.1581x; 1.0608x over previous
//
#include <hip/hip_runtime.h>
#include <math.h>

#define EPS 1e-5f

constexpr int Bc = 64, Pc = 68, Hc = 64, Wc = 64;
constexpr int NPIX  = Hc * Wc;   // 4096 pixels per tile
constexpr int NTILE = Bc * Pc;   // 4352 tiles
constexpr int BLK   = 256;       // threads per block
constexpr int PPT   = NPIX / BLK; // 16 pixels per thread

constexpr float LOG2E = 1.44269504088896340736f;
constexpr float LN2   = 0.69314718055994530942f;

// Block-wide sum reduction (256 threads = 4 waves of 64).
__device__ __forceinline__ float block_reduce_sum(float v, float* sbuf) {
    __syncthreads();  // protect sbuf from previous use
    #pragma unroll
    for (int o = 32; o > 0; o >>= 1) v += __shfl_down(v, o, 64);
    const int lane = threadIdx.x & 63;
    const int wid  = threadIdx.x >> 6;
    if (lane == 0) sbuf[wid] = v;
    __syncthreads();
    if (threadIdx.x == 0) {
        float s = sbuf[0] + sbuf[1] + sbuf[2] + sbuf[3];
        sbuf[4] = s;
    }
    __syncthreads();
    return sbuf[4];
}

__global__ __launch_bounds__(BLK)
void gauss_kld_tile_kernel(const float* __restrict__ hm,
                           const float* __restrict__ means,
                           const float* __restrict__ cov,
                           float* __restrict__ partial) {
    const int tile = blockIdx.x;
    const float* __restrict__ h = hm + (size_t)tile * NPIX;

    const float mx  = means[tile * 2 + 0];
    const float my  = means[tile * 2 + 1];
    const float s00 = cov[tile * 4 + 0];
    const float s01 = cov[tile * 4 + 1];
    const float s10 = cov[tile * 4 + 2];
    const float s11 = cov[tile * 4 + 3];
    const float det = s00 * s11 - s01 * s10 + EPS;
    // Fold -0.5 * log2(e) / det into the coefficients: per-pixel work in
    // pass 1 is then 2 FMA + 1 raw v_exp_f32 (exp2), no scale mul.
    const float kf  = -0.5f * LOG2E / det;
    const float c_xx =  kf * s11;
    const float c_xy = -kf * (s01 + s10);
    const float c_yy =  kf * s00;

    const int t = threadIdx.x;

    float ev[PPT];   // exp(log-prob), unnormalized — stored so pass 2 needs no exp
    float hv[PPT];
    float esum = 0.0f;
    float hsum = 0.0f;
    float hlog = 0.0f;   // sum h * log2(h) — computed here, hidden under loads

    // Coalesced float4 loads: float4 index v = k*256 + t, pixels [4v, 4v+4)
    #pragma unroll
    for (int k = 0; k < PPT / 4; k++) {
        const int v = k * BLK + t;
        const float4 h4 = reinterpret_cast<const float4*>(h)[v];
        hv[k * 4 + 0] = h4.x;
        hv[k * 4 + 1] = h4.y;
        hv[k * 4 + 2] = h4.z;
        hv[k * 4 + 3] = h4.w;
        const int base = v * 4;
        #pragma unroll
        for (int c = 0; c < 4; c++) {
            const int idx = base + c;
            const float dy = (float)(idx >> 6) - my;   // row = y
            const float dx = (float)(idx & 63) - mx;   // col = x
            // log2-domain log-prob: quad already scaled by -0.5*log2(e)
            const float l2 = fmaf(fmaf(c_xx, dx, c_xy * dy), dx, c_yy * dy * dy);
            const float e  = __builtin_amdgcn_exp2f(l2);
            ev[k * 4 + c] = e;
            esum += e;
        }
        // h-entropy terms here: hidden under global-load latency.
        // xlogy semantics: h==0 contributes 0 (0 * log2(1e-38) == 0).
        #pragma unroll
        for (int c = 0; c < 4; c++) {
            const float hh = hv[k * 4 + c];
            hsum += hh;
            hlog = fmaf(hh, __builtin_amdgcn_logf(fmaxf(hh, 1e-38f)), hlog);
        }
    }

    __shared__ float sbuf[8];
    const float S    = block_reduce_sum(esum, sbuf);
    // pr + EPS = (ev + EPS*S)/S  =>  ln(pr+EPS) = LN2*(log2(ev+cadd) - log2(S))
    const float cadd = EPS * S;
    const float l2S  = __builtin_amdgcn_logf(S);   // log2(S)

    // Pass 2: single v_log_f32 + FMA per pixel (was 2 logs + branch + mul).
    float kb = 0.0f;
    #pragma unroll
    for (int i = 0; i < PPT; i++) {
        kb = fmaf(hv[i], __builtin_amdgcn_logf(ev[i] + cadd), kb);
    }
    // sum h*ln(h) - h*ln(pr+EPS) = LN2 * (hlog - kb + log2(S)*hsum)
    const float contrib  = LN2 * fmaf(l2S, hsum, hlog - kb);
    const float tile_sum = block_reduce_sum(contrib, sbuf);
    if (threadIdx.x == 0) partial[tile] = tile_sum;
}

__global__ __launch_bounds__(BLK)
void gauss_kld_reduce_kernel(const float* __restrict__ partial,
                             float* __restrict__ out) {
    float s = 0.0f;
    for (int i = threadIdx.x; i < NTILE; i += BLK) s += partial[i];
    __shared__ float sbuf[8];
    const float tot = block_reduce_sum(s, sbuf);
    if (threadIdx.x == 0) out[0] = tot / (float)NTILE;
}

extern "C" void kernel_launch(void* const* d_in, const int* in_sizes, int n_in,
                              void* d_out, int out_size, void* d_ws, size_t ws_size,
                              hipStream_t stream) {
    const float* hm    = (const float*)d_in[0];
    const float* means = (const float*)d_in[1];
    const float* cov   = (const float*)d_in[2];
    float* out = (float*)d_out;
    float* partial = (float*)d_ws;  // NTILE floats

    gauss_kld_tile_kernel<<<NTILE, BLK, 0, stream>>>(hm, means, cov, partial);
    gauss_kld_reduce_kernel<<<1, BLK, 0, stream>>>(partial, out);
}